// Round 10
// baseline (387.546 us; speedup 1.0000x reference)
//
#include <hip/hip_runtime.h>
#include <cstdint>
#include <cstddef>

#define NTOK 8192
#define DMODEL 1024

typedef _Float16 half8 __attribute__((ext_vector_type(8)));
typedef short short8 __attribute__((ext_vector_type(8)));
typedef unsigned short ushort8v __attribute__((ext_vector_type(8)));
typedef float f32x4 __attribute__((ext_vector_type(4)));

using gptr_as1 = const __attribute__((address_space(1))) void*;
using lptr_as3 = __attribute__((address_space(3))) void*;

template <typename T> struct V8T;
template <> struct V8T<_Float16> { using type = half8; };
template <> struct V8T<short>    { using type = short8; };

__device__ __forceinline__ f32x4 mfma16(half8 a, half8 b, f32x4 c) {
  return __builtin_amdgcn_mfma_f32_16x16x32_f16(a, b, c, 0, 0, 0);
}
__device__ __forceinline__ f32x4 mfma16(short8 a, short8 b, f32x4 c) {
  return __builtin_amdgcn_mfma_f32_16x16x32_bf16(a, b, c, 0, 0, 0);
}

__device__ __forceinline__ unsigned short f2bf(float f) {
  unsigned u = __float_as_uint(f);
  u += 0x7fffu + ((u >> 16) & 1u);
  return (unsigned short)(u >> 16);
}

struct h4 { _Float16 x, y, z, w; };

__global__ void k_f32_to_f16(const float* __restrict__ in, h4* __restrict__ out, int n4) {
  int idx = blockIdx.x * blockDim.x + threadIdx.x;
  int stride = gridDim.x * blockDim.x;
  for (int i = idx; i < n4; i += stride) {
    float4 v = reinterpret_cast<const float4*>(in)[i];
    h4 o;
    o.x = (_Float16)v.x; o.y = (_Float16)v.y;
    o.z = (_Float16)v.z; o.w = (_Float16)v.w;
    out[i] = o;
  }
}

// all three weights -> packed fp16 [Wq;Wk;Wv], one launch (3*262144 float4)
__global__ __launch_bounds__(256) void k_w_to_f16(
    const float* __restrict__ wq, const float* __restrict__ wk,
    const float* __restrict__ wv, h4* __restrict__ out)
{
  int i = blockIdx.x * 256 + threadIdx.x;        // [0, 786432)
  const int seg = i >> 18;                       // 262144 float4 per weight
  const float* src = seg == 0 ? wq : (seg == 1 ? wk : wv);
  float4 v = reinterpret_cast<const float4*>(src)[i & 262143];
  h4 o;
  o.x = (_Float16)v.x; o.y = (_Float16)v.y;
  o.z = (_Float16)v.z; o.w = (_Float16)v.w;
  out[i] = o;
}

// ---------------------------------------------------------------------------
// 8-phase 256x256 GEMM, C = A @ B^T (A:[MxK] lda, B:[NxK] ldb, K-contiguous).
// R8-VERIFIED SYNC STRUCTURE — DO NOT TOUCH (R5/R7 raced on edits; R9's
// 2-phase variant measured ~16 µs slower: regime gate reproduced).
// Read-side facts: LDA4 reads sA[buf][wr] (own half) at ph1 (LO) and ph3
// (HI); LDB2 reads sB[buf][wc>>1] at ph1+ph2. Stage slots: ph1->A1(j+1),
// ph3->B0(j+2), ph4->B1(j+2)+A0(j+2). Boundary vmcnt(6).
// EPI 2: P = exp(C-40) bf16 [ld NTOK] via post-loop LDS-bounce vectorized
//        stores (R10) + 64-col partial row sums into C2.
//        Bounce safety: all K-loop LDS reads complete before ph4's opening
//        barrier at j=NT-1; regions are per-wave-private; own-wave lgkmcnt.
// EPI 3: raw fp32 C [ld DMODEL] to (z ? C2 : C)   (split-K PV partials)
// EPI 5: fused QKV: C=Q fp16, C2=K fp16, C3=V^T bf16 (transposed store)
// ---------------------------------------------------------------------------
template <typename T, int EPI>
__global__ __launch_bounds__(512, 2) void gemm8(
    const T* __restrict__ A, const T* __restrict__ B,
    void* __restrict__ C, void* __restrict__ C2, void* __restrict__ C3,
    int NT, int lda, int ldb, int kz)
{
  __shared__ __align__(16) T sA[2][2][8192];   // [buf][half][128x64 swizzled]
  __shared__ __align__(16) T sB[2][2][8192];

  const int tid  = threadIdx.x;
  const int lane = tid & 63;
  const int wave = tid >> 6;
  const int wr = wave >> 2, wc = wave & 3;     // 2M x 4N
  const int fq = lane >> 4, fr = lane & 15;

  const int brow = blockIdx.x * 256;
  const int bcol = blockIdx.y * 256;
  const int koff = blockIdx.z * kz;

  // swizzled fragment byte-element offset within a half (row fr, 16B at fq*8)
  const int foff = (fr * 32 + fq * 8) ^ ((fr & 8) ? 16 : 0);

  int rowc[2], colc[2];
#pragma unroll
  for (int i = 0; i < 2; ++i) {
    const int c = i * 512 + tid;
    const int pre = (c * 8) ^ (((c >> 5) & 1) << 4);
    const int s = pre >> 9, w = pre & 511;
    rowc[i] = (s >> 1) * 16 + (w >> 5);
    colc[i] = (s & 1) * 32 + (w & 31);
  }
  const T* pa0 = A + (size_t)(brow + rowc[0]) * lda + koff + colc[0];
  const T* pa1 = A + (size_t)(brow + rowc[1]) * lda + koff + colc[1];
  const T* pb0 = B + (size_t)(bcol + rowc[0]) * ldb + koff + colc[0];
  const T* pb1 = B + (size_t)(bcol + rowc[1]) * ldb + koff + colc[1];

#define STAGE(S, P0, P1, LDX, h, jj)                                          \
  do {                                                                        \
    __builtin_amdgcn_global_load_lds(                                         \
        (gptr_as1)(P0 + (size_t)(h) * 128 * (LDX) + (jj) * 64),               \
        (lptr_as3)&S[(jj) & 1][h][tid * 8], 16, 0, 0);                        \
    __builtin_amdgcn_global_load_lds(                                         \
        (gptr_as1)(P1 + (size_t)(h) * 128 * (LDX) + (jj) * 64),               \
        (lptr_as3)&S[(jj) & 1][h][(512 + tid) * 8], 16, 0, 0);                \
  } while (0)

  using VT = typename V8T<T>::type;
  VT av[4][2], bv[4][2];
  f32x4 acc[8][4] = {};

#define LDA4(mh)                                                              \
  _Pragma("unroll") for (int mm = 0; mm < 4; ++mm)                            \
  _Pragma("unroll") for (int kk = 0; kk < 2; ++kk)                            \
    av[mm][kk] = *reinterpret_cast<const VT*>(                                \
        &sA[buf][wr][(((mh) * 4 + mm) * 2 + kk) * 512 + foff]);

#define LDB2(nlo)                                                             \
  _Pragma("unroll") for (int nn = (nlo); nn < (nlo) + 2; ++nn)                \
  _Pragma("unroll") for (int kk = 0; kk < 2; ++kk)                            \
    bv[nn][kk] = *reinterpret_cast<const VT*>(                                \
        &sB[buf][wc >> 1][(((wc & 1) * 4 + nn) * 2 + kk) * 512 + foff]);

#define MF(mh, nlo)                                                           \
  _Pragma("unroll") for (int mm = 0; mm < 4; ++mm)                            \
  _Pragma("unroll") for (int nn = (nlo); nn < (nlo) + 2; ++nn)                \
  _Pragma("unroll") for (int kk = 0; kk < 2; ++kk)                            \
    acc[(mh) * 4 + mm][nn] = mfma16(av[mm][kk], bv[nn][kk],                   \
                                    acc[(mh) * 4 + mm][nn]);

#define LGKM0_FENCE()                                                         \
  asm volatile("s_waitcnt lgkmcnt(0)" ::: "memory");                          \
  __builtin_amdgcn_sched_barrier(0)

  // prologue: tile0 fully + tile1 {A0,B0,B1}; A1(1) staged at ph1 of j=0.
  STAGE(sA, pa0, pa1, lda, 0, 0);
  STAGE(sA, pa0, pa1, lda, 1, 0);
  STAGE(sB, pb0, pb1, ldb, 0, 0);
  STAGE(sB, pb0, pb1, ldb, 1, 0);
  if (NT > 1) {
    STAGE(sA, pa0, pa1, lda, 0, 1);
    STAGE(sB, pb0, pb1, ldb, 0, 1);
    STAGE(sB, pb0, pb1, ldb, 1, 1);
    asm volatile("s_waitcnt vmcnt(6)" ::: "memory");
  } else {
    asm volatile("s_waitcnt vmcnt(0)" ::: "memory");
  }
  __builtin_amdgcn_s_barrier();

  for (int j = 0; j < NT; ++j) {
    const int buf = j & 1;
    // ---- phase 1: read A-mh0(8) + B-n01(4); stage A1(j+1); MF(mh0,n01) ----
    LDA4(0);
    LDB2(0);
    if (j + 1 < NT) STAGE(sA, pa0, pa1, lda, 1, j + 1);
    __builtin_amdgcn_s_barrier();
    LGKM0_FENCE();
    __builtin_amdgcn_s_setprio(1);
    MF(0, 0);
    __builtin_amdgcn_s_setprio(0);
    __builtin_amdgcn_s_barrier();
    // ---- phase 2: read B-n23(4); MF(mh0,n23) ----
    LDB2(2);
    __builtin_amdgcn_s_barrier();
    LGKM0_FENCE();
    __builtin_amdgcn_s_setprio(1);
    MF(0, 2);
    __builtin_amdgcn_s_setprio(0);
    __builtin_amdgcn_s_barrier();
    // ---- phase 3: read A-mh1(8); stage B0(j+2); MF(mh1,n01) ----
    LDA4(1);
    if (j + 2 < NT) STAGE(sB, pb0, pb1, ldb, 0, j + 2);
    __builtin_amdgcn_s_barrier();
    LGKM0_FENCE();
    __builtin_amdgcn_s_setprio(1);
    MF(1, 0);
    __builtin_amdgcn_s_setprio(0);
    __builtin_amdgcn_s_barrier();
    // ---- phase 4: stage B1(j+2) + A0(j+2); MF(mh1,n23); boundary vmcnt ----
    if (j + 2 < NT) {
      STAGE(sB, pb0, pb1, ldb, 1, j + 2);
      STAGE(sA, pa0, pa1, lda, 0, j + 2);
    }
    __builtin_amdgcn_s_barrier();
    LGKM0_FENCE();
    __builtin_amdgcn_s_setprio(1);
    MF(1, 2);
    __builtin_amdgcn_s_setprio(0);
    if (j + 2 < NT)
      asm volatile("s_waitcnt vmcnt(6)" ::: "memory");
    else if (j + 1 < NT)
      asm volatile("s_waitcnt vmcnt(0)" ::: "memory");
    if (j + 1 < NT) __builtin_amdgcn_s_barrier();
  }
#undef STAGE
#undef LDA4
#undef LDB2
#undef MF
#undef LGKM0_FENCE

  // epilogue: C/D layout col=lane&15, row=(lane>>4)*4+j (m89-verified)
  if constexpr (EPI == 2) {
    unsigned short* Cc = (unsigned short*)C;
    float* Pl = (float*)C2;
    // per-wave private 16KB bounce region (all K-loop LDS reads completed
    // before ph4's opening barrier; regions disjoint per wave)
    unsigned short* lp = (wave < 4)
        ? (unsigned short*)sA + wave * 8192
        : (unsigned short*)sB + (wave - 4) * 8192;
    float ps[8][4];
#pragma unroll
    for (int m = 0; m < 8; ++m)
#pragma unroll
      for (int j = 0; j < 4; ++j) ps[m][j] = 0.f;
#pragma unroll
    for (int m = 0; m < 8; ++m) {
#pragma unroll
      for (int n = 0; n < 4; ++n) {
#pragma unroll
        for (int j = 0; j < 4; ++j) {
          // exp(S - 40) = exp2(S*log2e - 40*log2e)
          float e = exp2f(acc[m][n][j] * 1.4426950408889634f - 57.707801635558536f);
          ps[m][j] += e;
          const int rl = m * 16 + fq * 4 + j;     // 0..127 within wave tile
          const int cl = n * 16 + fr;             // 0..63
          const int blk = (cl >> 3) ^ (rl & 7);   // bank-spread 8-col blocks
          lp[rl * 64 + blk * 8 + (cl & 7)] = f2bf(e);
        }
      }
    }
    // rowsum reduce across the 16 fr lanes; fr==0 stores the 64-col partial
#pragma unroll
    for (int m = 0; m < 8; ++m)
#pragma unroll
      for (int j = 0; j < 4; ++j) {
        float s = ps[m][j];
        s += __shfl_xor(s, 1, 64);
        s += __shfl_xor(s, 2, 64);
        s += __shfl_xor(s, 4, 64);
        s += __shfl_xor(s, 8, 64);
        ps[m][j] = s;
      }
    if (fr == 0) {
      const int pidx = blockIdx.y * 4 + wc;   // 64-col slice index (128 total)
#pragma unroll
      for (int m = 0; m < 8; ++m) {
        const int r0 = brow + wr * 128 + m * 16 + fq * 4;
#pragma unroll
        for (int j = 0; j < 4; ++j)
          Pl[(size_t)pidx * NTOK + r0 + j] = ps[m][j];
      }
    }
    // read back own region (conflict-free swizzle) and store 16B-coalesced
    asm volatile("s_waitcnt lgkmcnt(0)" ::: "memory");
#pragma unroll
    for (int rr = 0; rr < 16; ++rr) {
      const int rl  = rr * 8 + (lane >> 3);
      const int blk = (lane & 7) ^ (rl & 7);
      ushort8v v = *reinterpret_cast<const ushort8v*>(&lp[rl * 64 + blk * 8]);
      const int grow = brow + wr * 128 + rl;
      const int gcol = bcol + wc * 64 + (lane & 7) * 8;
      *reinterpret_cast<ushort8v*>(&Cc[(size_t)grow * NTOK + gcol]) = v;
    }
  } else if constexpr (EPI == 3) {
    float* Cc = (float*)(blockIdx.z ? C2 : C);
#pragma unroll
    for (int m = 0; m < 8; ++m)
#pragma unroll
      for (int n = 0; n < 4; ++n) {
        const int r0 = brow + wr * 128 + m * 16 + fq * 4;
        const int c  = bcol + wc * 64 + n * 16 + fr;
#pragma unroll
        for (int j = 0; j < 4; ++j)
          Cc[(size_t)(r0 + j) * DMODEL + c] = acc[m][n][j];
      }
  } else {  // EPI 5: fused QKV, block-uniform branch (bcol 256-aligned)
    const int seg = bcol >> 10;                 // 0:Q 1:K 2:V
    const int cb  = bcol & 1023;
    if (seg == 0) {
      _Float16* Cc = (_Float16*)C;
#pragma unroll
      for (int m = 0; m < 8; ++m)
#pragma unroll
        for (int n = 0; n < 4; ++n) {
          const int r0 = brow + wr * 128 + m * 16 + fq * 4;
          const int c  = cb + wc * 64 + n * 16 + fr;
#pragma unroll
          for (int j = 0; j < 4; ++j)
            Cc[(size_t)(r0 + j) * DMODEL + c] = (_Float16)acc[m][n][j];
        }
    } else if (seg == 1) {
      _Float16* Cc = (_Float16*)C2;
#pragma unroll
      for (int m = 0; m < 8; ++m)
#pragma unroll
        for (int n = 0; n < 4; ++n) {
          const int r0 = brow + wr * 128 + m * 16 + fq * 4;
          const int c  = cb + wc * 64 + n * 16 + fr;
#pragma unroll
          for (int j = 0; j < 4; ++j)
            Cc[(size_t)(r0 + j) * DMODEL + c] = (_Float16)acc[m][n][j];
        }
    } else {
      unsigned short* Cc = (unsigned short*)C3;
#pragma unroll
      for (int m = 0; m < 8; ++m)
#pragma unroll
        for (int n = 0; n < 4; ++n) {
          const int r0 = brow + wr * 128 + m * 16 + fq * 4;
          const int c  = cb + wc * 64 + n * 16 + fr;
          ushort4 pk;
          pk.x = f2bf(acc[m][n][0]); pk.y = f2bf(acc[m][n][1]);
          pk.z = f2bf(acc[m][n][2]); pk.w = f2bf(acc[m][n][3]);
          *reinterpret_cast<ushort4*>(&Cc[(size_t)c * NTOK + r0]) = pk;
        }
    }
  }
}

// l[r] = sum over 128 column-slice partials
__global__ __launch_bounds__(256) void k_reduce_l(
    const float* __restrict__ Pl, float* __restrict__ l, int rows)
{
  int r = blockIdx.x * 256 + threadIdx.x;
  if (r < rows) {
    float s = 0.f;
#pragma unroll 8
    for (int p = 0; p < 128; ++p) s += Pl[(size_t)p * NTOK + r];
    l[r] = s;
  }
}

// out = (out + p1) / l[row]   (1024 fp32 per row -> 256 float4 per row)
__global__ __launch_bounds__(256) void k_combine(
    float* __restrict__ out, const float* __restrict__ p1,
    const float* __restrict__ l, int n4)
{
  int idx = blockIdx.x * blockDim.x + threadIdx.x;
  int stride = gridDim.x * blockDim.x;
  for (int i = idx; i < n4; i += stride) {
    float4 a = reinterpret_cast<float4*>(out)[i];
    float4 b = reinterpret_cast<const float4*>(p1)[i];
    float inv = 1.0f / l[i >> 8];
    a.x = (a.x + b.x) * inv; a.y = (a.y + b.y) * inv;
    a.z = (a.z + b.z) * inv; a.w = (a.w + b.w) * inv;
    reinterpret_cast<float4*>(out)[i] = a;
  }
}

extern "C" void kernel_launch(void* const* d_in, const int* in_sizes, int n_in,
                              void* d_out, int out_size, void* d_ws, size_t ws_size,
                              hipStream_t stream)
{
  const float* x  = (const float*)d_in[0];
  const float* Wq = (const float*)d_in[1];
  const float* Wk = (const float*)d_in[2];
  const float* Wv = (const float*)d_in[3];
  float* out = (float*)d_out;
  char* ws = (char*)d_ws;

  // workspace layout (bytes):
  //  [0,16M)   xh fp16   (dead after proj; overlaid by p1 in PV)
  //  [16M,22M) packed W fp16 (dead after proj; overlaid by Pl after QK)
  //  [22M,38M) Q fp16
  //  [38M,54M) K fp16
  //  [54M,70M) V^T bf16 [1024][8192]
  //  [70M,+32K) l fp32
  //  [72M,200M) P bf16 [8192][8192]
  _Float16* xh  = (_Float16*)(ws);
  _Float16* wpk = (_Float16*)(ws + (16u << 20));
  _Float16* qh  = (_Float16*)(ws + (22u << 20));
  _Float16* kh  = (_Float16*)(ws + (38u << 20));
  unsigned short* vt = (unsigned short*)(ws + (54u << 20));
  float* l  = (float*)(ws + (70u << 20));
  float* Pl = (float*)(ws + (16u << 20));   // overlays wpk (dead by QK time)
  unsigned short* P = (unsigned short*)(ws + (72u << 20));
  float* p1 = (float*)ws;                   // overlays xh (dead by PV time)

  // 1) fp32 -> fp16 conversions (weights packed [Wq;Wk;Wv] = [3072][1024])
  k_f32_to_f16<<<2048, 256, 0, stream>>>(x, (h4*)xh, NTOK * DMODEL / 4);
  k_w_to_f16<<<3072, 256, 0, stream>>>(Wq, Wk, Wv, (h4*)wpk);

  // 2) fused QKV projection: grid 32x12 (N=3072), NT = 1024/64 = 16
  gemm8<_Float16, 5><<<dim3(32, 12), 512, 0, stream>>>(
      xh, wpk, qh, kh, vt, 16, DMODEL, DMODEL, 0);

  // 3) P = exp(Q K^T - 40) bf16 + fused partial row sums; grid 32x32
  gemm8<_Float16, 2><<<dim3(32, 32), 512, 0, stream>>>(
      qh, kh, P, Pl, nullptr, 16, DMODEL, DMODEL, 0);
  k_reduce_l<<<NTOK / 256, 256, 0, stream>>>(Pl, l, NTOK);

  // 4) PV split-K=2 (R8-verified): grid 32x4x2 = 256 blocks; raw partials
  gemm8<short, 3><<<dim3(32, 4, 2), 512, 0, stream>>>(
      (const short*)P, (const short*)vt, out, p1, nullptr,
      64, NTOK, NTOK, NTOK / 2);
  k_combine<<<2048, 256, 0, stream>>>(out, p1, l, NTOK * DMODEL / 4);
}

// Round 11
// 379.909 us; speedup vs baseline: 1.0201x; 1.0201x over previous
//
#include <hip/hip_runtime.h>
#include <cstdint>
#include <cstddef>

#define NTOK 8192
#define DMODEL 1024

typedef _Float16 half8 __attribute__((ext_vector_type(8)));
typedef short short8 __attribute__((ext_vector_type(8)));
typedef float f32x4 __attribute__((ext_vector_type(4)));

using gptr_as1 = const __attribute__((address_space(1))) void*;
using lptr_as3 = __attribute__((address_space(3))) void*;

template <typename T> struct V8T;
template <> struct V8T<_Float16> { using type = half8; };
template <> struct V8T<short>    { using type = short8; };

__device__ __forceinline__ f32x4 mfma16(half8 a, half8 b, f32x4 c) {
  return __builtin_amdgcn_mfma_f32_16x16x32_f16(a, b, c, 0, 0, 0);
}
__device__ __forceinline__ f32x4 mfma16(short8 a, short8 b, f32x4 c) {
  return __builtin_amdgcn_mfma_f32_16x16x32_bf16(a, b, c, 0, 0, 0);
}

__device__ __forceinline__ unsigned short f2bf(float f) {
  unsigned u = __float_as_uint(f);
  u += 0x7fffu + ((u >> 16) & 1u);
  return (unsigned short)(u >> 16);
}

struct h4 { _Float16 x, y, z, w; };

__global__ void k_f32_to_f16(const float* __restrict__ in, h4* __restrict__ out, int n4) {
  int idx = blockIdx.x * blockDim.x + threadIdx.x;
  int stride = gridDim.x * blockDim.x;
  for (int i = idx; i < n4; i += stride) {
    float4 v = reinterpret_cast<const float4*>(in)[i];
    h4 o;
    o.x = (_Float16)v.x; o.y = (_Float16)v.y;
    o.z = (_Float16)v.z; o.w = (_Float16)v.w;
    out[i] = o;
  }
}

// all three weights -> packed fp16 [Wq;Wk;Wv], one launch (3*262144 float4)
__global__ __launch_bounds__(256) void k_w_to_f16(
    const float* __restrict__ wq, const float* __restrict__ wk,
    const float* __restrict__ wv, h4* __restrict__ out)
{
  int i = blockIdx.x * 256 + threadIdx.x;        // [0, 786432)
  const int seg = i >> 18;                       // 262144 float4 per weight
  const float* src = seg == 0 ? wq : (seg == 1 ? wk : wv);
  float4 v = reinterpret_cast<const float4*>(src)[i & 262143];
  h4 o;
  o.x = (_Float16)v.x; o.y = (_Float16)v.y;
  o.z = (_Float16)v.z; o.w = (_Float16)v.w;
  out[i] = o;
}

// ---------------------------------------------------------------------------
// 8-phase 256x256 GEMM, C = A @ B^T (A:[MxK] lda, B:[NxK] ldb, K-contiguous).
// R8-VERIFIED SYNC STRUCTURE — DO NOT TOUCH.
//   R5 raced (removed ph3/ph4 fences); R7 raced (staged A0 at ph2 while A
//   still live through ph3); R9's 2-phase PV variant: −16 µs (regime gate);
//   R10's LDS-bounce epilogue: −12 µs (stores weren't the constraint).
// Read-side facts: LDA4 reads sA[buf][wr] (own half) at ph1 (LO) and ph3
// (HI); LDB2 reads sB[buf][wc>>1] at ph1+ph2. Stage slots: ph1->A1(j+1),
// ph3->B0(j+2), ph4->B1(j+2)+A0(j+2). Boundary vmcnt(6).
// EPI 2: P = exp(C-40) bf16 [ld NTOK] + 64-col partial row sums into C2
// EPI 3: raw fp32 C [ld DMODEL] to (z ? C2 : C)   (split-K PV partials)
// EPI 5: fused QKV: C=Q fp16, C2=K fp16, C3=V^T bf16 (transposed store)
// ---------------------------------------------------------------------------
template <typename T, int EPI>
__global__ __launch_bounds__(512, 2) void gemm8(
    const T* __restrict__ A, const T* __restrict__ B,
    void* __restrict__ C, void* __restrict__ C2, void* __restrict__ C3,
    int NT, int lda, int ldb, int kz)
{
  __shared__ __align__(16) T sA[2][2][8192];   // [buf][half][128x64 swizzled]
  __shared__ __align__(16) T sB[2][2][8192];

  const int tid  = threadIdx.x;
  const int lane = tid & 63;
  const int wave = tid >> 6;
  const int wr = wave >> 2, wc = wave & 3;     // 2M x 4N
  const int fq = lane >> 4, fr = lane & 15;

  const int brow = blockIdx.x * 256;
  const int bcol = blockIdx.y * 256;
  const int koff = blockIdx.z * kz;

  // swizzled fragment byte-element offset within a half (row fr, 16B at fq*8)
  const int foff = (fr * 32 + fq * 8) ^ ((fr & 8) ? 16 : 0);

  int rowc[2], colc[2];
#pragma unroll
  for (int i = 0; i < 2; ++i) {
    const int c = i * 512 + tid;
    const int pre = (c * 8) ^ (((c >> 5) & 1) << 4);
    const int s = pre >> 9, w = pre & 511;
    rowc[i] = (s >> 1) * 16 + (w >> 5);
    colc[i] = (s & 1) * 32 + (w & 31);
  }
  const T* pa0 = A + (size_t)(brow + rowc[0]) * lda + koff + colc[0];
  const T* pa1 = A + (size_t)(brow + rowc[1]) * lda + koff + colc[1];
  const T* pb0 = B + (size_t)(bcol + rowc[0]) * ldb + koff + colc[0];
  const T* pb1 = B + (size_t)(bcol + rowc[1]) * ldb + koff + colc[1];

#define STAGE(S, P0, P1, LDX, h, jj)                                          \
  do {                                                                        \
    __builtin_amdgcn_global_load_lds(                                         \
        (gptr_as1)(P0 + (size_t)(h) * 128 * (LDX) + (jj) * 64),               \
        (lptr_as3)&S[(jj) & 1][h][tid * 8], 16, 0, 0);                        \
    __builtin_amdgcn_global_load_lds(                                         \
        (gptr_as1)(P1 + (size_t)(h) * 128 * (LDX) + (jj) * 64),               \
        (lptr_as3)&S[(jj) & 1][h][(512 + tid) * 8], 16, 0, 0);                \
  } while (0)

  using VT = typename V8T<T>::type;
  VT av[4][2], bv[4][2];
  f32x4 acc[8][4] = {};

#define LDA4(mh)                                                              \
  _Pragma("unroll") for (int mm = 0; mm < 4; ++mm)                            \
  _Pragma("unroll") for (int kk = 0; kk < 2; ++kk)                            \
    av[mm][kk] = *reinterpret_cast<const VT*>(                                \
        &sA[buf][wr][(((mh) * 4 + mm) * 2 + kk) * 512 + foff]);

#define LDB2(nlo)                                                             \
  _Pragma("unroll") for (int nn = (nlo); nn < (nlo) + 2; ++nn)                \
  _Pragma("unroll") for (int kk = 0; kk < 2; ++kk)                            \
    bv[nn][kk] = *reinterpret_cast<const VT*>(                                \
        &sB[buf][wc >> 1][(((wc & 1) * 4 + nn) * 2 + kk) * 512 + foff]);

#define MF(mh, nlo)                                                           \
  _Pragma("unroll") for (int mm = 0; mm < 4; ++mm)                            \
  _Pragma("unroll") for (int nn = (nlo); nn < (nlo) + 2; ++nn)                \
  _Pragma("unroll") for (int kk = 0; kk < 2; ++kk)                            \
    acc[(mh) * 4 + mm][nn] = mfma16(av[mm][kk], bv[nn][kk],                   \
                                    acc[(mh) * 4 + mm][nn]);

#define LGKM0_FENCE()                                                         \
  asm volatile("s_waitcnt lgkmcnt(0)" ::: "memory");                          \
  __builtin_amdgcn_sched_barrier(0)

  // prologue: tile0 fully + tile1 {A0,B0,B1}; A1(1) staged at ph1 of j=0.
  STAGE(sA, pa0, pa1, lda, 0, 0);
  STAGE(sA, pa0, pa1, lda, 1, 0);
  STAGE(sB, pb0, pb1, ldb, 0, 0);
  STAGE(sB, pb0, pb1, ldb, 1, 0);
  if (NT > 1) {
    STAGE(sA, pa0, pa1, lda, 0, 1);
    STAGE(sB, pb0, pb1, ldb, 0, 1);
    STAGE(sB, pb0, pb1, ldb, 1, 1);
    asm volatile("s_waitcnt vmcnt(6)" ::: "memory");
  } else {
    asm volatile("s_waitcnt vmcnt(0)" ::: "memory");
  }
  __builtin_amdgcn_s_barrier();

  for (int j = 0; j < NT; ++j) {
    const int buf = j & 1;
    // ---- phase 1: read A-mh0(8) + B-n01(4); stage A1(j+1); MF(mh0,n01) ----
    LDA4(0);
    LDB2(0);
    if (j + 1 < NT) STAGE(sA, pa0, pa1, lda, 1, j + 1);
    __builtin_amdgcn_s_barrier();
    LGKM0_FENCE();
    __builtin_amdgcn_s_setprio(1);
    MF(0, 0);
    __builtin_amdgcn_s_setprio(0);
    __builtin_amdgcn_s_barrier();
    // ---- phase 2: read B-n23(4); MF(mh0,n23) ----
    LDB2(2);
    __builtin_amdgcn_s_barrier();
    LGKM0_FENCE();
    __builtin_amdgcn_s_setprio(1);
    MF(0, 2);
    __builtin_amdgcn_s_setprio(0);
    __builtin_amdgcn_s_barrier();
    // ---- phase 3: read A-mh1(8); stage B0(j+2); MF(mh1,n01) ----
    LDA4(1);
    if (j + 2 < NT) STAGE(sB, pb0, pb1, ldb, 0, j + 2);
    __builtin_amdgcn_s_barrier();
    LGKM0_FENCE();
    __builtin_amdgcn_s_setprio(1);
    MF(1, 0);
    __builtin_amdgcn_s_setprio(0);
    __builtin_amdgcn_s_barrier();
    // ---- phase 4: stage B1(j+2) + A0(j+2); MF(mh1,n23); boundary vmcnt ----
    if (j + 2 < NT) {
      STAGE(sB, pb0, pb1, ldb, 1, j + 2);
      STAGE(sA, pa0, pa1, lda, 0, j + 2);
    }
    __builtin_amdgcn_s_barrier();
    LGKM0_FENCE();
    __builtin_amdgcn_s_setprio(1);
    MF(1, 2);
    __builtin_amdgcn_s_setprio(0);
    if (j + 2 < NT)
      asm volatile("s_waitcnt vmcnt(6)" ::: "memory");
    else if (j + 1 < NT)
      asm volatile("s_waitcnt vmcnt(0)" ::: "memory");
    if (j + 1 < NT) __builtin_amdgcn_s_barrier();
  }
#undef STAGE
#undef LDA4
#undef LDB2
#undef MF
#undef LGKM0_FENCE

  // epilogue: C/D layout col=lane&15, row=(lane>>4)*4+j (m89-verified)
  if constexpr (EPI == 2) {
    unsigned short* Cc = (unsigned short*)C;
    float* Pl = (float*)C2;
    float ps[8][4];
#pragma unroll
    for (int m = 0; m < 8; ++m)
#pragma unroll
      for (int j = 0; j < 4; ++j) ps[m][j] = 0.f;
#pragma unroll
    for (int m = 0; m < 8; ++m) {
#pragma unroll
      for (int n = 0; n < 4; ++n) {
        const int r0 = brow + wr * 128 + m * 16 + fq * 4;
        const int c  = bcol + wc * 64 + n * 16 + fr;
#pragma unroll
        for (int j = 0; j < 4; ++j) {
          // exp(S - 40) = exp2(S*log2e - 40*log2e)
          float e = exp2f(acc[m][n][j] * 1.4426950408889634f - 57.707801635558536f);
          Cc[(size_t)(r0 + j) * NTOK + c] = f2bf(e);
          ps[m][j] += e;
        }
      }
    }
#pragma unroll
    for (int m = 0; m < 8; ++m)
#pragma unroll
      for (int j = 0; j < 4; ++j) {
        float s = ps[m][j];
        s += __shfl_xor(s, 1, 64);
        s += __shfl_xor(s, 2, 64);
        s += __shfl_xor(s, 4, 64);
        s += __shfl_xor(s, 8, 64);
        ps[m][j] = s;
      }
    if (fr == 0) {
      const int pidx = blockIdx.y * 4 + wc;   // 64-col slice index (128 total)
#pragma unroll
      for (int m = 0; m < 8; ++m) {
        const int r0 = brow + wr * 128 + m * 16 + fq * 4;
#pragma unroll
        for (int j = 0; j < 4; ++j)
          Pl[(size_t)pidx * NTOK + r0 + j] = ps[m][j];
      }
    }
  } else if constexpr (EPI == 3) {
    float* Cc = (float*)(blockIdx.z ? C2 : C);
#pragma unroll
    for (int m = 0; m < 8; ++m)
#pragma unroll
      for (int n = 0; n < 4; ++n) {
        const int r0 = brow + wr * 128 + m * 16 + fq * 4;
        const int c  = bcol + wc * 64 + n * 16 + fr;
#pragma unroll
        for (int j = 0; j < 4; ++j)
          Cc[(size_t)(r0 + j) * DMODEL + c] = acc[m][n][j];
      }
  } else {  // EPI 5: fused QKV, block-uniform branch (bcol 256-aligned)
    const int seg = bcol >> 10;                 // 0:Q 1:K 2:V
    const int cb  = bcol & 1023;
    if (seg == 0) {
      _Float16* Cc = (_Float16*)C;
#pragma unroll
      for (int m = 0; m < 8; ++m)
#pragma unroll
        for (int n = 0; n < 4; ++n) {
          const int r0 = brow + wr * 128 + m * 16 + fq * 4;
          const int c  = cb + wc * 64 + n * 16 + fr;
#pragma unroll
          for (int j = 0; j < 4; ++j)
            Cc[(size_t)(r0 + j) * DMODEL + c] = (_Float16)acc[m][n][j];
        }
    } else if (seg == 1) {
      _Float16* Cc = (_Float16*)C2;
#pragma unroll
      for (int m = 0; m < 8; ++m)
#pragma unroll
        for (int n = 0; n < 4; ++n) {
          const int r0 = brow + wr * 128 + m * 16 + fq * 4;
          const int c  = cb + wc * 64 + n * 16 + fr;
#pragma unroll
          for (int j = 0; j < 4; ++j)
            Cc[(size_t)(r0 + j) * DMODEL + c] = (_Float16)acc[m][n][j];
        }
    } else {
      unsigned short* Cc = (unsigned short*)C3;
#pragma unroll
      for (int m = 0; m < 8; ++m)
#pragma unroll
        for (int n = 0; n < 4; ++n) {
          const int r0 = brow + wr * 128 + m * 16 + fq * 4;
          const int c  = cb + wc * 64 + n * 16 + fr;
          ushort4 pk;
          pk.x = f2bf(acc[m][n][0]); pk.y = f2bf(acc[m][n][1]);
          pk.z = f2bf(acc[m][n][2]); pk.w = f2bf(acc[m][n][3]);
          *reinterpret_cast<ushort4*>(&Cc[(size_t)c * NTOK + r0]) = pk;
        }
    }
  }
}

// linv[r] = 1 / (sum over 128 column-slice partials)
__global__ __launch_bounds__(256) void k_reduce_l(
    const float* __restrict__ Pl, float* __restrict__ linv, int rows)
{
  int r = blockIdx.x * 256 + threadIdx.x;
  if (r < rows) {
    float s = 0.f;
#pragma unroll 8
    for (int p = 0; p < 128; ++p) s += Pl[(size_t)p * NTOK + r];
    linv[r] = 1.0f / s;
  }
}

// out = (out + p1) * linv[row]   (1024 fp32 per row -> 256 float4 per row)
__global__ __launch_bounds__(256) void k_combine(
    float* __restrict__ out, const float* __restrict__ p1,
    const float* __restrict__ linv, int n4)
{
  int idx = blockIdx.x * blockDim.x + threadIdx.x;
  int stride = gridDim.x * blockDim.x;
  for (int i = idx; i < n4; i += stride) {
    float4 a = reinterpret_cast<float4*>(out)[i];
    float4 b = reinterpret_cast<const float4*>(p1)[i];
    float inv = linv[i >> 8];
    a.x = (a.x + b.x) * inv; a.y = (a.y + b.y) * inv;
    a.z = (a.z + b.z) * inv; a.w = (a.w + b.w) * inv;
    reinterpret_cast<float4*>(out)[i] = a;
  }
}

extern "C" void kernel_launch(void* const* d_in, const int* in_sizes, int n_in,
                              void* d_out, int out_size, void* d_ws, size_t ws_size,
                              hipStream_t stream)
{
  const float* x  = (const float*)d_in[0];
  const float* Wq = (const float*)d_in[1];
  const float* Wk = (const float*)d_in[2];
  const float* Wv = (const float*)d_in[3];
  float* out = (float*)d_out;
  char* ws = (char*)d_ws;

  // workspace layout (bytes):
  //  [0,16M)   xh fp16   (dead after proj; overlaid by p1 in PV)
  //  [16M,22M) packed W fp16 (dead after proj; overlaid by Pl after QK)
  //  [22M,38M) Q fp16
  //  [38M,54M) K fp16
  //  [54M,70M) V^T bf16 [1024][8192]
  //  [70M,+32K) linv fp32
  //  [72M,200M) P bf16 [8192][8192]
  _Float16* xh  = (_Float16*)(ws);
  _Float16* wpk = (_Float16*)(ws + (16u << 20));
  _Float16* qh  = (_Float16*)(ws + (22u << 20));
  _Float16* kh  = (_Float16*)(ws + (38u << 20));
  unsigned short* vt = (unsigned short*)(ws + (54u << 20));
  float* l  = (float*)(ws + (70u << 20));
  float* Pl = (float*)(ws + (16u << 20));   // overlays wpk (dead by QK time)
  unsigned short* P = (unsigned short*)(ws + (72u << 20));
  float* p1 = (float*)ws;                   // overlays xh (dead by PV time)

  // 1) fp32 -> fp16 conversions (weights packed [Wq;Wk;Wv] = [3072][1024])
  k_f32_to_f16<<<2048, 256, 0, stream>>>(x, (h4*)xh, NTOK * DMODEL / 4);
  k_w_to_f16<<<3072, 256, 0, stream>>>(Wq, Wk, Wv, (h4*)wpk);

  // 2) fused QKV projection: grid 32x12 (N=3072), NT = 1024/64 = 16
  gemm8<_Float16, 5><<<dim3(32, 12), 512, 0, stream>>>(
      xh, wpk, qh, kh, vt, 16, DMODEL, DMODEL, 0);

  // 3) P = exp(Q K^T - 40) bf16 + fused partial row sums; grid 32x32
  gemm8<_Float16, 2><<<dim3(32, 32), 512, 0, stream>>>(
      qh, kh, P, Pl, nullptr, 16, DMODEL, DMODEL, 0);
  k_reduce_l<<<NTOK / 256, 256, 0, stream>>>(Pl, l, NTOK);

  // 4) PV split-K=2 (R8-verified): grid 32x4x2 = 256 blocks; raw partials
  gemm8<short, 3><<<dim3(32, 4, 2), 512, 0, stream>>>(
      (const short*)P, (const short*)vt, out, p1, nullptr,
      64, NTOK, NTOK, NTOK / 2);
  k_combine<<<2048, 256, 0, stream>>>(out, p1, l, NTOK * DMODEL / 4);
}